// Round 6
// baseline (3661.012 us; speedup 1.0000x reference)
//
#include <hip/hip_runtime.h>
#include <hip/hip_bf16.h>

// Mean-shift: 3 iterations of X <- eta * X @ (K/deg) + (1-eta) * X,
// K = exp(2 * X^T X), D=32, N=9216. Fused attention formulation.
// R6: megakernel — all phases (pack, 3x msattn, 3x reduce) in ONE launch with
// hand-rolled grid barriers (device-scope atomics + __threadfence, the
// grid.sync mechanism). Co-residency guaranteed: 1008 blocks, 34.8 KB LDS +
// launch_bounds(256,4) -> 4 blocks/CU = 1024 slots. Kills ~6 graph-node gaps
// and cross-phase cold-cache effects. den now computed by MFMA with a
// ones-B-fragment (removes per-chunk VALU adds + epilogue shuffle reduce).
// msattn core unchanged from R5: 4 waves x 32 queries, shared double-buffered
// LDS key tiles in MFMA read order (conflict-free), key-interleaved b64 P
// stores, KSEG=14 key segments with fp32 partials.

#define DIM 32
#define RESO 96
#define NPT (RESO * RESO)          // 9216
#define NITER 3
#define ETA 0.5f
#define SCALE 2.88539008f          // BW * log2(e) = 2 * 1.4426950408

#define QB 128                     // queries per block (4 waves x 32)
#define NWAVE 4
#define NQB (NPT / QB)             // 72
#define KSEG 14                    // key segments
#define NBLK (NQB * KSEG)          // 1008 blocks (<= 256 CU x 4)
#define NCHUNK_TOT (NPT / 64)      // 144 chunks of 64 keys
#define PSTRIDE 72                 // P-slab row stride (144 B, 16B-aligned)
#define DN (DIM * NPT)             // 294912

typedef __bf16 bf16_t;
typedef __bf16 v8bf __attribute__((ext_vector_type(8)));
typedef float  v4f  __attribute__((ext_vector_type(4)));

__device__ __forceinline__ void grid_barrier(unsigned int* c, unsigned int target) {
    __threadfence();
    __syncthreads();
    if (threadIdx.x == 0) {
        __hip_atomic_fetch_add(c, 1u, __ATOMIC_ACQ_REL, __HIP_MEMORY_SCOPE_AGENT);
        while (__hip_atomic_load(c, __ATOMIC_ACQUIRE, __HIP_MEMORY_SCOPE_AGENT) < target)
            __builtin_amdgcn_s_sleep(2);
    }
    __syncthreads();
    __threadfence();
}

// One mean-shift attention pass over this block's (qb, ks) assignment.
__device__ __forceinline__ void msattn_phase(
        const float* __restrict__ Xcur,
        const bf16_t* __restrict__ rows,
        const bf16_t* __restrict__ cols,
        float* __restrict__ part_num,
        float* __restrict__ part_den,
        bf16_t (*tiles)[4096], bf16_t* pslab_base,
        int qb, int ks, int tid) {
    const int w    = tid >> 6;
    const int lane = tid & 63;
    const int quad = lane >> 4;
    const int l16  = lane & 15;
    const int c0   = (NCHUNK_TOT * ks) / KSEG;
    const int c1   = (NCHUNK_TOT * (ks + 1)) / KSEG;
    const int q0w  = qb * QB + w * 32;

    bf16_t* p_lds = pslab_base + w * (32 * PSTRIDE);

    // A-frags: strip e covers queries q0w+e*16+m; A[m=l16][k=quad*8+j],
    // BW*log2e folded in.
    v8bf afrag0, afrag1;
#pragma unroll
    for (int j = 0; j < 8; ++j) {
        const float* src = Xcur + (quad * 8 + j) * NPT + q0w + l16;
        afrag0[j] = (bf16_t)(src[0] * SCALE);
        afrag1[j] = (bf16_t)(src[16] * SCALE);
    }

    // ones B-fragment for MFMA-den (D[q][n] = sum_k P[q][k], all n equal)
    v8bf ones;
#pragma unroll
    for (int j = 0; j < 8; ++j) ones[j] = (bf16_t)1.0f;

    // Staging: 8 pieces of 1KB per chunk; wave w stages pieces 2w, 2w+1.
    const bf16_t* gsrc[2];
    int gdelta[2], ldst[2];
#pragma unroll
    for (int i = 0; i < 2; ++i) {
        int p = 2 * w + i;
        if (p < 4) {       // tileA subtile t=p: key c*64+4*l16+p, dims quad*8..
            gsrc[i] = rows + ((size_t)c0 * 64 + 4 * l16 + p) * DIM + quad * 8;
            gdelta[i] = 64 * DIM;
            ldst[i] = p * 512 + lane * 8;
        } else {           // tileB frag r=p-4=(h<<1|g): dim h*16+l16, keys c*64+g*32+quad*8..
            int r = p - 4, h = r >> 1, g = r & 1;
            gsrc[i] = cols + (size_t)(h * 16 + l16) * NPT + c0 * 64 + g * 32 + quad * 8;
            gdelta[i] = 64;
            ldst[i] = 2048 + r * 512 + lane * 8;
        }
    }

    v4f acc00 = {0.f, 0.f, 0.f, 0.f};   // strip 0, dims 0..15
    v4f acc01 = {0.f, 0.f, 0.f, 0.f};   // strip 0, dims 16..31
    v4f acc10 = {0.f, 0.f, 0.f, 0.f};   // strip 1, dims 0..15
    v4f acc11 = {0.f, 0.f, 0.f, 0.f};   // strip 1, dims 16..31
    v4f dden0 = {0.f, 0.f, 0.f, 0.f};   // den, strip 0 (MFMA-ones)
    v4f dden1 = {0.f, 0.f, 0.f, 0.f};   // den, strip 1

    // Prologue: stage first chunk into buffer 0.
#pragma unroll
    for (int i = 0; i < 2; ++i) {
        v8bf st = *(const v8bf*)gsrc[i];
        gsrc[i] += gdelta[i];
        *(v8bf*)&tiles[0][ldst[i]] = st;
    }
    __syncthreads();

    for (int c = c0; c < c1; ++c) {
        const int cc = c - c0;
        const bf16_t* tb = tiles[cc & 1];
        const bool more = (c + 1 < c1);

        v8bf stn0, stn1;
        if (more) {
            stn0 = *(const v8bf*)gsrc[0]; gsrc[0] += gdelta[0];
            stn1 = *(const v8bf*)gsrc[1]; gsrc[1] += gdelta[1];
        }

        // --- GEMM1: each tile read feeds both strips ---
        v4f s0[4], s1[4];
#pragma unroll
        for (int t = 0; t < 4; ++t) {
            v8bf b = *(const v8bf*)&tb[t * 512 + lane * 8];
            s0[t] = __builtin_amdgcn_mfma_f32_16x16x32_bf16(afrag0, b,
                                                            (v4f){0.f, 0.f, 0.f, 0.f}, 0, 0, 0);
            s1[t] = __builtin_amdgcn_mfma_f32_16x16x32_bf16(afrag1, b,
                                                            (v4f){0.f, 0.f, 0.f, 0.f}, 0, 0, 0);
        }

        // --- exp2 + b64-packed P stores (position 4*l16+t <-> key, identity) ---
#pragma unroll
        for (int r = 0; r < 4; ++r) {
            union { bf16_t h[4]; unsigned long long u; } pk0, pk1;
#pragma unroll
            for (int t = 0; t < 4; ++t) {
                pk0.h[t] = (bf16_t)__builtin_amdgcn_exp2f(s0[t][r]);
                pk1.h[t] = (bf16_t)__builtin_amdgcn_exp2f(s1[t][r]);
            }
            *(unsigned long long*)&p_lds[(quad * 4 + r) * PSTRIDE + 4 * l16] = pk0.u;
            *(unsigned long long*)&p_lds[(16 + quad * 4 + r) * PSTRIDE + 4 * l16] = pk1.u;
        }

        // --- GEMM2 + MFMA-den; tileB reads shared by strips ---
        v8bf b00 = *(const v8bf*)&tb[2048 + 0 * 512 + lane * 8];  // dims 0-15,  keys 0-31
        v8bf b01 = *(const v8bf*)&tb[2048 + 1 * 512 + lane * 8];  // dims 0-15,  keys 32-63
        v8bf b10 = *(const v8bf*)&tb[2048 + 2 * 512 + lane * 8];  // dims 16-31, keys 0-31
        v8bf b11 = *(const v8bf*)&tb[2048 + 3 * 512 + lane * 8];  // dims 16-31, keys 32-63
        {
            v8bf a20 = *(const v8bf*)&p_lds[l16 * PSTRIDE + quad * 8];
            v8bf a21 = *(const v8bf*)&p_lds[l16 * PSTRIDE + 32 + quad * 8];
            acc00 = __builtin_amdgcn_mfma_f32_16x16x32_bf16(a20, b00, acc00, 0, 0, 0);
            acc01 = __builtin_amdgcn_mfma_f32_16x16x32_bf16(a20, b10, acc01, 0, 0, 0);
            acc00 = __builtin_amdgcn_mfma_f32_16x16x32_bf16(a21, b01, acc00, 0, 0, 0);
            acc01 = __builtin_amdgcn_mfma_f32_16x16x32_bf16(a21, b11, acc01, 0, 0, 0);
            dden0 = __builtin_amdgcn_mfma_f32_16x16x32_bf16(a20, ones, dden0, 0, 0, 0);
            dden0 = __builtin_amdgcn_mfma_f32_16x16x32_bf16(a21, ones, dden0, 0, 0, 0);
        }
        {
            v8bf a20 = *(const v8bf*)&p_lds[(16 + l16) * PSTRIDE + quad * 8];
            v8bf a21 = *(const v8bf*)&p_lds[(16 + l16) * PSTRIDE + 32 + quad * 8];
            acc10 = __builtin_amdgcn_mfma_f32_16x16x32_bf16(a20, b00, acc10, 0, 0, 0);
            acc11 = __builtin_amdgcn_mfma_f32_16x16x32_bf16(a20, b10, acc11, 0, 0, 0);
            acc10 = __builtin_amdgcn_mfma_f32_16x16x32_bf16(a21, b01, acc10, 0, 0, 0);
            acc11 = __builtin_amdgcn_mfma_f32_16x16x32_bf16(a21, b11, acc11, 0, 0, 0);
            dden1 = __builtin_amdgcn_mfma_f32_16x16x32_bf16(a20, ones, dden1, 0, 0, 0);
            dden1 = __builtin_amdgcn_mfma_f32_16x16x32_bf16(a21, ones, dden1, 0, 0, 0);
        }

        if (more) {
            *(v8bf*)&tiles[(cc + 1) & 1][ldst[0]] = stn0;
            *(v8bf*)&tiles[(cc + 1) & 1][ldst[1]] = stn1;
        }
        __syncthreads();
    }

    // --- epilogue: write partials; den already per-query in dden[r] ---
    float* pn = part_num + (size_t)ks * DN;
#pragma unroll
    for (int r = 0; r < 4; ++r) {
        int gq0 = q0w + quad * 4 + r;
        int gq1 = gq0 + 16;
        pn[(size_t)gq0 * DIM + l16]      = acc00[r];
        pn[(size_t)gq0 * DIM + 16 + l16] = acc01[r];
        pn[(size_t)gq1 * DIM + l16]      = acc10[r];
        pn[(size_t)gq1 * DIM + 16 + l16] = acc11[r];
    }
    if (l16 == 0) {
#pragma unroll
        for (int r = 0; r < 4; ++r) {
            part_den[ks * NPT + q0w + quad * 4 + r]      = dden0[r];
            part_den[ks * NPT + q0w + 16 + quad * 4 + r] = dden1[r];
        }
    }
}

// Reduce KSEG partials for 32 queries, apply eta-step, write Xnext + next
// iteration's bf16 rows/cols. sh = 2144 floats of scratch (aliases tiles).
__device__ __forceinline__ void reduce_phase(
        const float* __restrict__ part_num,
        const float* __restrict__ part_den,
        const float* __restrict__ Xcur,
        float* __restrict__ Xnext,
        bf16_t* __restrict__ rows_out,
        bf16_t* __restrict__ cols_out,
        float* sh, int blk, int tid) {
    float* tnum = sh;          // [32][33]
    float* txn  = sh + 1056;   // [32][33]
    float* tden = sh + 2112;   // [32]
    const int q0 = blk * 32;

    // pass 1 (q-major, coalesced partial reads)
#pragma unroll
    for (int j = 0; j < 4; ++j) {
        int idx = tid + j * 256;
        int qq = idx >> 5, d = idx & 31;
        float s = 0.f;
#pragma unroll
        for (int ss = 0; ss < KSEG; ++ss)
            s += part_num[((size_t)ss * NPT + q0 + qq) * DIM + d];
        tnum[qq * 33 + d] = s;
    }
    if (tid < 32) {
        float s = 0.f;
#pragma unroll
        for (int ss = 0; ss < KSEG; ++ss)
            s += part_den[ss * NPT + q0 + tid];
        tden[tid] = s;
    }
    __syncthreads();

    // pass 2 (d-major: Xcur read, Xnext + cols_out writes coalesced)
#pragma unroll
    for (int j = 0; j < 4; ++j) {
        int idx = tid + j * 256;
        int d = idx >> 5, qq = idx & 31;
        float num = tnum[qq * 33 + d];
        float dn  = tden[qq];
        float xo  = Xcur[d * NPT + q0 + qq];
        float xn  = ETA * num / dn + (1.0f - ETA) * xo;
        Xnext[d * NPT + q0 + qq] = xn;
        cols_out[(size_t)d * NPT + q0 + qq] = (bf16_t)xn;
        txn[qq * 33 + d] = xn;
    }
    __syncthreads();

    // pass 3 (q-major: rows_out coalesced)
#pragma unroll
    for (int j = 0; j < 4; ++j) {
        int idx = tid + j * 256;
        int qq = idx >> 5, d = idx & 31;
        rows_out[(size_t)(q0 + qq) * DIM + d] = (bf16_t)txn[qq * 33 + d];
    }
}

__global__ __launch_bounds__(256, 4)
void mega_kernel(const float* __restrict__ x_in,
                 float* __restrict__ out,
                 bf16_t* __restrict__ rows0, bf16_t* __restrict__ cols0,
                 bf16_t* __restrict__ rows1, bf16_t* __restrict__ cols1,
                 float* __restrict__ part_num, float* __restrict__ part_den,
                 unsigned int* __restrict__ ctr) {
    // LDS: tiles 16 KB + pslab 18 KB = 34.8 KB -> 4 blocks/CU.
    __shared__ __align__(16) bf16_t tiles[2][4096];
    __shared__ __align__(16) bf16_t pslab[NWAVE][32 * PSTRIDE];

    const int tid = threadIdx.x;
    const int blk = blockIdx.x;

    // --- phase 0: pack x_in -> bf16 rows0/cols0, copy to out slice 0 ---
    for (int idx = blk * 256 + tid; idx < DN; idx += NBLK * 256) {
        int d = idx / NPT, n = idx - d * NPT;
        float v = x_in[idx];
        cols0[idx] = (bf16_t)v;
        rows0[(size_t)n * DIM + d] = (bf16_t)v;
        out[idx] = v;
    }
    grid_barrier(&ctr[0], NBLK);

    const int qb = blk % NQB;
    const int ks = blk / NQB;

    for (int it = 0; it < NITER; ++it) {
        const float* Xcur = (it == 0) ? x_in : out + (size_t)it * DN;
        const bf16_t* rin = (it & 1) ? rows1 : rows0;
        const bf16_t* cin = (it & 1) ? cols1 : cols0;
        bf16_t* rout = (it & 1) ? rows0 : rows1;
        bf16_t* cout = (it & 1) ? cols0 : cols1;

        msattn_phase(Xcur, rin, cin, part_num, part_den,
                     tiles, &pslab[0][0], qb, ks, tid);
        grid_barrier(&ctr[1 + 2 * it], NBLK);

        if (blk < NPT / 32)
            reduce_phase(part_num, part_den, Xcur, out + (size_t)(it + 1) * DN,
                         rout, cout, (float*)tiles, blk, tid);
        grid_barrier(&ctr[2 + 2 * it], NBLK);
    }
}

extern "C" void kernel_launch(void* const* d_in, const int* in_sizes, int n_in,
                              void* d_out, int out_size, void* d_ws, size_t ws_size,
                              hipStream_t stream) {
    const float* x_in = (const float*)d_in[0];
    float* out = (float*)d_out;

    bf16_t* rows0 = (bf16_t*)d_ws;
    bf16_t* cols0 = rows0 + DN;
    bf16_t* rows1 = cols0 + DN;
    bf16_t* cols1 = rows1 + DN;
    float* part_num = (float*)(cols1 + DN);                 // KSEG * DN f32
    float* part_den = part_num + (size_t)KSEG * DN;         // KSEG * NPT f32
    // barrier counters, 256B-aligned
    size_t ctr_off = (((size_t)(part_den + KSEG * NPT) - (size_t)d_ws) + 255) & ~(size_t)255;
    unsigned int* ctr = (unsigned int*)((char*)d_ws + ctr_off);

    hipMemsetAsync(ctr, 0, 128, stream);
    mega_kernel<<<NBLK, 256, 0, stream>>>(x_in, out, rows0, cols0, rows1, cols1,
                                          part_num, part_den, ctr);
}

// Round 7
// 138.526 us; speedup vs baseline: 26.4283x; 26.4283x over previous
//
#include <hip/hip_runtime.h>
#include <hip/hip_bf16.h>

// Mean-shift: 3 iterations of X <- eta * X @ (K/deg) + (1-eta) * X,
// K = exp(2 * X^T X), D=32, N=9216. Fused attention formulation.
// R7: R6's megakernel grid-barriers caused L2-invalidate storms (non-coherent
// per-XCD L2) -> 25x regression; reverted to multi-kernel (launches are the
// grid barrier). This round = R4 structure (KSEG=7 cheap partials) + R5's
// 32 queries/wave dual strip (every tile b128 read feeds 2 MFMAs, ~40% less
// LDS read traffic per query) + R6's MFMA-ones den (no VALU den adds, no
// epilogue shuffles; verified identical absmax). QB=256: grid 36x7=252
// blocks x 8 waves ~= 1 block/CU. Tiles in MFMA read order (conflict-free);
// key-interleaved b64 P stores (identity position<->key map).

#define DIM 32
#define RESO 96
#define NPT (RESO * RESO)          // 9216
#define NITER 3
#define ETA 0.5f
#define SCALE 2.88539008f          // BW * log2(e) = 2 * 1.4426950408

#define QB 256                     // queries per block (8 waves x 32)
#define NWAVE 8
#define NQB (NPT / QB)             // 36
#define KSEG 7                     // key segments (grid.y)
#define NCHUNK_TOT (NPT / 64)      // 144 chunks of 64 keys
#define PSTRIDE 72                 // P-slab row stride in elems (144 B, 16B-aligned)

typedef __bf16 bf16_t;
typedef __bf16 v8bf __attribute__((ext_vector_type(8)));
typedef float  v4f  __attribute__((ext_vector_type(4)));

// One-time pack of fp32 X (DIM x NPT) into bf16 row-major (NPT x DIM) and
// bf16 col-major (DIM x NPT); also copies X into d_out slice 0.
__global__ void pack_kernel(const float* __restrict__ X,
                            bf16_t* __restrict__ rows,
                            bf16_t* __restrict__ cols,
                            float* __restrict__ out_copy) {
    int idx = blockIdx.x * 256 + threadIdx.x;
    if (idx >= DIM * NPT) return;
    int d = idx / NPT;
    int n = idx - d * NPT;
    float v = X[idx];
    cols[idx] = (bf16_t)v;
    rows[n * DIM + d] = (bf16_t)v;
    out_copy[idx] = v;
}

// Fused mean-shift partial kernel. Block = 512 thr = 8 waves; wave w owns 32
// queries [qb*256 + w*32, +32) as two 16-row MFMA strips sharing every tile
// read. All waves consume the same 64-key chunk from shared double-buffered
// LDS tiles (one barrier per chunk); wave w stages tile piece w. Block covers
// key segment ks; writes fp32 num/den partials.
__global__ __launch_bounds__(512, 2)
void msattn_kernel(const float* __restrict__ Xcur,
                   const bf16_t* __restrict__ rows,
                   const bf16_t* __restrict__ cols,
                   float* __restrict__ part_num,
                   float* __restrict__ part_den) {
    // tiles[buf]: [0..2047] = tileA (GEMM1 B, read-order; subtile t at t*512,
    // lane off lane*8): element = key kc+4*l16+t, dims quad*8.. ;
    // [2048..4095] = tileB (GEMM2 B; frag r=(h<<1|g) at 2048+r*512): element =
    // V^T[dim h*16+l16][keys kc+g*32+quad*8..]. Lane i reads base+i*16B: no
    // bank conflicts by construction.
    __shared__ __align__(16) bf16_t tiles[2][4096];
    __shared__ __align__(16) bf16_t pslab[NWAVE][32 * PSTRIDE];

    const int tid  = threadIdx.x;
    const int w    = tid >> 6;
    const int lane = tid & 63;
    const int quad = lane >> 4;
    const int l16  = lane & 15;
    const int qb   = blockIdx.x;
    const int ks   = blockIdx.y;
    const int c0   = (NCHUNK_TOT * ks) / KSEG;
    const int c1   = (NCHUNK_TOT * (ks + 1)) / KSEG;
    const int q0w  = qb * QB + w * 32;

    bf16_t* p_lds = pslab[w];

    // A-frags: strip e covers queries q0w+e*16+m; A[m=l16][k=quad*8+j],
    // BW*log2e folded in.
    v8bf afrag0, afrag1;
#pragma unroll
    for (int j = 0; j < 8; ++j) {
        const float* src = Xcur + (quad * 8 + j) * NPT + q0w + l16;
        afrag0[j] = (bf16_t)(src[0] * SCALE);
        afrag1[j] = (bf16_t)(src[16] * SCALE);
    }

    // ones B-fragment for MFMA-den (D[q][n] = sum_k P[q][k], all cols equal)
    v8bf ones;
#pragma unroll
    for (int j = 0; j < 8; ++j) ones[j] = (bf16_t)1.0f;

    // Staging: 8 pieces of 1KB per chunk; wave w stages piece w.
    const bf16_t* gsrc;
    int gdelta, ldst;
    if (w < 4) {           // tileA subtile t=w: key c*64+4*l16+w, dims quad*8..
        gsrc = rows + ((size_t)c0 * 64 + 4 * l16 + w) * DIM + quad * 8;
        gdelta = 64 * DIM;
        ldst = w * 512 + lane * 8;
    } else {               // tileB frag r=w-4=(h<<1|g): dim h*16+l16, keys c*64+g*32+quad*8..
        int r = w - 4, h = r >> 1, g = r & 1;
        gsrc = cols + (size_t)(h * 16 + l16) * NPT + c0 * 64 + g * 32 + quad * 8;
        gdelta = 64;
        ldst = 2048 + r * 512 + lane * 8;
    }

    v4f acc00 = {0.f, 0.f, 0.f, 0.f};   // strip 0, dims 0..15
    v4f acc01 = {0.f, 0.f, 0.f, 0.f};   // strip 0, dims 16..31
    v4f acc10 = {0.f, 0.f, 0.f, 0.f};   // strip 1, dims 0..15
    v4f acc11 = {0.f, 0.f, 0.f, 0.f};   // strip 1, dims 16..31
    v4f dden0 = {0.f, 0.f, 0.f, 0.f};   // den, strip 0 (MFMA-ones)
    v4f dden1 = {0.f, 0.f, 0.f, 0.f};   // den, strip 1

    // Prologue: stage first chunk into buffer 0.
    {
        v8bf st = *(const v8bf*)gsrc;
        gsrc += gdelta;
        *(v8bf*)&tiles[0][ldst] = st;
    }
    __syncthreads();

    for (int c = c0; c < c1; ++c) {
        const int cc = c - c0;
        const bf16_t* tb = tiles[cc & 1];
        const bool more = (c + 1 < c1);

        v8bf stn;
        if (more) { stn = *(const v8bf*)gsrc; gsrc += gdelta; }

        // --- GEMM1: each tile read feeds both strips ---
        v4f s0[4], s1[4];
#pragma unroll
        for (int t = 0; t < 4; ++t) {
            v8bf b = *(const v8bf*)&tb[t * 512 + lane * 8];
            s0[t] = __builtin_amdgcn_mfma_f32_16x16x32_bf16(afrag0, b,
                                                            (v4f){0.f, 0.f, 0.f, 0.f}, 0, 0, 0);
            s1[t] = __builtin_amdgcn_mfma_f32_16x16x32_bf16(afrag1, b,
                                                            (v4f){0.f, 0.f, 0.f, 0.f}, 0, 0, 0);
        }

        // --- exp2 + b64-packed P stores (position 4*l16+t <-> key, identity) ---
#pragma unroll
        for (int r = 0; r < 4; ++r) {
            union { bf16_t h[4]; unsigned long long u; } pk0, pk1;
#pragma unroll
            for (int t = 0; t < 4; ++t) {
                pk0.h[t] = (bf16_t)__builtin_amdgcn_exp2f(s0[t][r]);
                pk1.h[t] = (bf16_t)__builtin_amdgcn_exp2f(s1[t][r]);
            }
            *(unsigned long long*)&p_lds[(quad * 4 + r) * PSTRIDE + 4 * l16] = pk0.u;
            *(unsigned long long*)&p_lds[(16 + quad * 4 + r) * PSTRIDE + 4 * l16] = pk1.u;
        }

        // --- GEMM2 + MFMA-den; tileB reads shared by both strips ---
        v8bf b00 = *(const v8bf*)&tb[2048 + 0 * 512 + lane * 8];  // dims 0-15,  keys 0-31
        v8bf b01 = *(const v8bf*)&tb[2048 + 1 * 512 + lane * 8];  // dims 0-15,  keys 32-63
        v8bf b10 = *(const v8bf*)&tb[2048 + 2 * 512 + lane * 8];  // dims 16-31, keys 0-31
        v8bf b11 = *(const v8bf*)&tb[2048 + 3 * 512 + lane * 8];  // dims 16-31, keys 32-63
        {
            v8bf a20 = *(const v8bf*)&p_lds[l16 * PSTRIDE + quad * 8];
            v8bf a21 = *(const v8bf*)&p_lds[l16 * PSTRIDE + 32 + quad * 8];
            acc00 = __builtin_amdgcn_mfma_f32_16x16x32_bf16(a20, b00, acc00, 0, 0, 0);
            acc01 = __builtin_amdgcn_mfma_f32_16x16x32_bf16(a20, b10, acc01, 0, 0, 0);
            acc00 = __builtin_amdgcn_mfma_f32_16x16x32_bf16(a21, b01, acc00, 0, 0, 0);
            acc01 = __builtin_amdgcn_mfma_f32_16x16x32_bf16(a21, b11, acc01, 0, 0, 0);
            dden0 = __builtin_amdgcn_mfma_f32_16x16x32_bf16(a20, ones, dden0, 0, 0, 0);
            dden0 = __builtin_amdgcn_mfma_f32_16x16x32_bf16(a21, ones, dden0, 0, 0, 0);
        }
        {
            v8bf a20 = *(const v8bf*)&p_lds[(16 + l16) * PSTRIDE + quad * 8];
            v8bf a21 = *(const v8bf*)&p_lds[(16 + l16) * PSTRIDE + 32 + quad * 8];
            acc10 = __builtin_amdgcn_mfma_f32_16x16x32_bf16(a20, b00, acc10, 0, 0, 0);
            acc11 = __builtin_amdgcn_mfma_f32_16x16x32_bf16(a20, b10, acc11, 0, 0, 0);
            acc10 = __builtin_amdgcn_mfma_f32_16x16x32_bf16(a21, b01, acc10, 0, 0, 0);
            acc11 = __builtin_amdgcn_mfma_f32_16x16x32_bf16(a21, b11, acc11, 0, 0, 0);
            dden1 = __builtin_amdgcn_mfma_f32_16x16x32_bf16(a20, ones, dden1, 0, 0, 0);
            dden1 = __builtin_amdgcn_mfma_f32_16x16x32_bf16(a21, ones, dden1, 0, 0, 0);
        }

        if (more) *(v8bf*)&tiles[(cc + 1) & 1][ldst] = stn;
        __syncthreads();
    }

    // --- epilogue: write partials; den already per-query in dden[r] ---
    float* pn = part_num + (size_t)ks * NPT * DIM;
#pragma unroll
    for (int r = 0; r < 4; ++r) {
        int gq0 = q0w + quad * 4 + r;
        int gq1 = gq0 + 16;
        pn[(size_t)gq0 * DIM + l16]      = acc00[r];
        pn[(size_t)gq0 * DIM + 16 + l16] = acc01[r];
        pn[(size_t)gq1 * DIM + l16]      = acc10[r];
        pn[(size_t)gq1 * DIM + 16 + l16] = acc11[r];
    }
    if (l16 == 0) {
#pragma unroll
        for (int r = 0; r < 4; ++r) {
            part_den[ks * NPT + q0w + quad * 4 + r]      = dden0[r];
            part_den[ks * NPT + q0w + 16 + quad * 4 + r] = dden1[r];
        }
    }
}

// Reduce KSEG partials, apply eta-step, write Xnext + next iteration's bf16
// rows/cols. Tiled 32q x 32d with LDS transpose so every global access is
// coalesced. Grid = NPT/32 = 288 blocks x 256 threads.
__global__ __launch_bounds__(256, 4)
void reduce_kernel(const float* __restrict__ part_num,
                   const float* __restrict__ part_den,
                   const float* __restrict__ Xcur,
                   float* __restrict__ Xnext,
                   bf16_t* __restrict__ rows_out,
                   bf16_t* __restrict__ cols_out) {
    __shared__ float tnum[32][33];
    __shared__ float txn[32][33];
    __shared__ float tden[32];

    const int tid = threadIdx.x;
    const int q0  = blockIdx.x * 32;

    // pass 1 (q-major, coalesced partial reads)
#pragma unroll
    for (int j = 0; j < 4; ++j) {
        int idx = tid + j * 256;
        int qq = idx >> 5, d = idx & 31;
        float s = 0.f;
#pragma unroll
        for (int ss = 0; ss < KSEG; ++ss)
            s += part_num[((size_t)ss * NPT + q0 + qq) * DIM + d];
        tnum[qq][d] = s;
    }
    if (tid < 32) {
        float s = 0.f;
#pragma unroll
        for (int ss = 0; ss < KSEG; ++ss)
            s += part_den[ss * NPT + q0 + tid];
        tden[tid] = s;
    }
    __syncthreads();

    // pass 2 (d-major: Xcur read, Xnext + cols_out writes coalesced)
#pragma unroll
    for (int j = 0; j < 4; ++j) {
        int idx = tid + j * 256;
        int d = idx >> 5, qq = idx & 31;
        float num = tnum[qq][d];
        float dn  = tden[qq];
        float xo  = Xcur[d * NPT + q0 + qq];
        float xn  = ETA * num / dn + (1.0f - ETA) * xo;
        Xnext[d * NPT + q0 + qq] = xn;
        cols_out[(size_t)d * NPT + q0 + qq] = (bf16_t)xn;
        txn[qq][d] = xn;
    }
    __syncthreads();

    // pass 3 (q-major: rows_out coalesced)
#pragma unroll
    for (int j = 0; j < 4; ++j) {
        int idx = tid + j * 256;
        int qq = idx >> 5, d = idx & 31;
        rows_out[(size_t)(q0 + qq) * DIM + d] = (bf16_t)txn[qq][d];
    }
}

extern "C" void kernel_launch(void* const* d_in, const int* in_sizes, int n_in,
                              void* d_out, int out_size, void* d_ws, size_t ws_size,
                              hipStream_t stream) {
    const float* x_in = (const float*)d_in[0];
    float* out = (float*)d_out;

    const size_t DN = (size_t)DIM * NPT;
    // Workspace: 4 bf16 pack buffers (ping-pong), fp32 partials.
    bf16_t* rows0 = (bf16_t*)d_ws;
    bf16_t* cols0 = rows0 + DN;
    bf16_t* rows1 = cols0 + DN;
    bf16_t* cols1 = rows1 + DN;
    float* part_num = (float*)(cols1 + DN);                 // KSEG * NPT * DIM f32
    float* part_den = part_num + (size_t)KSEG * NPT * DIM;  // KSEG * NPT f32

    const int pack_blocks = (DIM * NPT + 255) / 256;   // 1152
    pack_kernel<<<pack_blocks, 256, 0, stream>>>(x_in, rows0, cols0, out);

    for (int it = 0; it < NITER; ++it) {
        const float* Xcur = (it == 0) ? x_in : out + (size_t)it * DN;
        bf16_t* rin  = (it & 1) ? rows1 : rows0;
        bf16_t* cin  = (it & 1) ? cols1 : cols0;
        bf16_t* rout = (it & 1) ? rows0 : rows1;
        bf16_t* cout = (it & 1) ? cols0 : cols1;
        msattn_kernel<<<dim3(NQB, KSEG), 512, 0, stream>>>(Xcur, rin, cin,
                                                           part_num, part_den);
        reduce_kernel<<<NPT / 32, 256, 0, stream>>>(part_num, part_den, Xcur,
                                                    out + (size_t)(it + 1) * DN,
                                                    rout, cout);
    }
}